// Round 1
// baseline (454.445 us; speedup 1.0000x reference)
//
#include <hip/hip_runtime.h>
#include <hip/hip_bf16.h>

#define N_NODES 8192
#define F_IN 512
#define F_OUT 256
#define KSPLIT 4
#define KCHUNK (N_NODES / KSPLIT)

using short8 = __attribute__((ext_vector_type(8))) short;
using f32x4  = __attribute__((ext_vector_type(4))) float;

__device__ __forceinline__ short f2bf(float v) {
    union { float f; unsigned u; } x; x.f = v;
    unsigned r = x.u + 0x7fffu + ((x.u >> 16) & 1u);   // RNE
    return (short)(r >> 16);
}

// A0: w1 = W@a1, w2 = W@a2 (fp32, exact scores via associativity), WTg[c][k] = bf16(W[k][c])
__global__ void k_prep(const float* __restrict__ W, const float* __restrict__ a1,
                       const float* __restrict__ a2, float* __restrict__ w1,
                       float* __restrict__ w2, short* __restrict__ WTg) {
    const int k = blockIdx.x;          // 0..511
    const int l = threadIdx.x;         // 0..63
    float4 wv = *(const float4*)(W + (size_t)k * F_OUT + 4 * l);
    float4 av = *(const float4*)(a1 + 4 * l);
    float4 bv = *(const float4*)(a2 + 4 * l);
    float s1 = wv.x*av.x + wv.y*av.y + wv.z*av.z + wv.w*av.w;
    float s2 = wv.x*bv.x + wv.y*bv.y + wv.z*bv.z + wv.w*bv.w;
    WTg[(size_t)(4*l+0)*F_IN + k] = f2bf(wv.x);
    WTg[(size_t)(4*l+1)*F_IN + k] = f2bf(wv.y);
    WTg[(size_t)(4*l+2)*F_IN + k] = f2bf(wv.z);
    WTg[(size_t)(4*l+3)*F_IN + k] = f2bf(wv.w);
    #pragma unroll
    for (int off = 32; off; off >>= 1) {
        s1 += __shfl_down(s1, off);
        s2 += __shfl_down(s2, off);
    }
    if (l == 0) { w1[k] = s1; w2[k] = s2; }
}

// A1: f1 = x@w1, f2 = x@w2 (one wave per row)
__global__ void k_f12(const float* __restrict__ x, const float* __restrict__ w1,
                      const float* __restrict__ w2, float* __restrict__ f1,
                      float* __restrict__ f2) {
    const int wv = threadIdx.x >> 6, l = threadIdx.x & 63;
    const int i = blockIdx.x * 4 + wv;
    const float* xr = x + (size_t)i * F_IN;
    float s1 = 0.f, s2 = 0.f;
    #pragma unroll
    for (int t = 0; t < 2; ++t) {
        int k = t * 256 + l * 4;
        float4 xv = *(const float4*)(xr + k);
        float4 u  = *(const float4*)(w1 + k);
        float4 v  = *(const float4*)(w2 + k);
        s1 += xv.x*u.x + xv.y*u.y + xv.z*u.z + xv.w*u.w;
        s2 += xv.x*v.x + xv.y*v.y + xv.z*v.z + xv.w*v.w;
    }
    #pragma unroll
    for (int off = 32; off; off >>= 1) {
        s1 += __shfl_down(s1, off);
        s2 += __shfl_down(s2, off);
    }
    if (l == 0) { f1[i] = s1; f2[i] = s2; }
}

// A1b: F2max = max over all f2 (global softmax shift: valid upper bound, softmax is shift-invariant)
__global__ void k_f2max(const float* __restrict__ f2, float* __restrict__ F2max) {
    const int t = threadIdx.x;
    float m = -3.4e38f;
    for (int i = t; i < N_NODES; i += 1024) m = fmaxf(m, f2[i]);
    #pragma unroll
    for (int off = 32; off; off >>= 1) m = fmaxf(m, __shfl_down(m, off));
    __shared__ float sm[16];
    if ((t & 63) == 0) sm[t >> 6] = m;
    __syncthreads();
    if (t == 0) {
        float mm = sm[0];
        #pragma unroll
        for (int w = 1; w < 16; ++w) mm = fmaxf(mm, sm[w]);
        *F2max = mm;
    }
}

// A2: hT[c][i] = bf16( sum_k x[i][k] W[k][c] ), via MFMA; D[m=c][n=i]
__launch_bounds__(256)
__global__ void k_hT(const float* __restrict__ x, const short* __restrict__ WTg,
                     short* __restrict__ hT) {
    __shared__ short x_lds[32 * 64];    // [i][k] 128B rows, chunk^row XOR swizzle
    __shared__ short wt_lds[256 * 64];  // [c][k]
    const int tid = threadIdx.x;
    const int wv = tid >> 6, l = tid & 63, lg = l >> 4, lr = l & 15;
    const int ibase = blockIdx.x * 32;
    f32x4 acc[4][2];
    #pragma unroll
    for (int a = 0; a < 4; ++a)
        #pragma unroll
        for (int b = 0; b < 2; ++b) acc[a][b] = (f32x4){0.f, 0.f, 0.f, 0.f};
    for (int k0 = 0; k0 < F_IN; k0 += 64) {
        __syncthreads();
        {   // stage x tile [32][64] as bf16
            int i = tid >> 3, ch = tid & 7;
            const float* src = x + (size_t)(ibase + i) * F_IN + k0 + ch * 8;
            float4 v0 = *(const float4*)(src);
            float4 v1 = *(const float4*)(src + 4);
            short8 s;
            s[0]=f2bf(v0.x); s[1]=f2bf(v0.y); s[2]=f2bf(v0.z); s[3]=f2bf(v0.w);
            s[4]=f2bf(v1.x); s[5]=f2bf(v1.y); s[6]=f2bf(v1.z); s[7]=f2bf(v1.w);
            *(short8*)&x_lds[i * 64 + 8 * (ch ^ (i & 7))] = s;
        }
        {   // stage WT tile [256][64]
            int cb = tid >> 3, ch = tid & 7;
            #pragma unroll
            for (int p = 0; p < 8; ++p) {
                int c = cb + 32 * p;
                short8 s = *(const short8*)(WTg + (size_t)c * F_IN + k0 + ch * 8);
                *(short8*)&wt_lds[c * 64 + 8 * (ch ^ (c & 7))] = s;
            }
        }
        __syncthreads();
        #pragma unroll
        for (int ks = 0; ks < 2; ++ks) {
            short8 bfrag[2], afrag[4];
            #pragma unroll
            for (int it = 0; it < 2; ++it) {
                int i = it * 16 + lr;
                bfrag[it] = *(short8*)&x_lds[i * 64 + 8 * ((lg + 4*ks) ^ (i & 7))];
            }
            #pragma unroll
            for (int ct = 0; ct < 4; ++ct) {
                int c = wv * 64 + ct * 16 + lr;
                afrag[ct] = *(short8*)&wt_lds[c * 64 + 8 * ((lg + 4*ks) ^ (c & 7))];
            }
            #pragma unroll
            for (int ct = 0; ct < 4; ++ct)
                #pragma unroll
                for (int it = 0; it < 2; ++it)
                    acc[ct][it] = __builtin_amdgcn_mfma_f32_16x16x32_bf16(
                        afrag[ct], bfrag[it], acc[ct][it], 0, 0, 0);
        }
    }
    #pragma unroll
    for (int ct = 0; ct < 4; ++ct)
        #pragma unroll
        for (int it = 0; it < 2; ++it)
            #pragma unroll
            for (int r = 0; r < 4; ++r) {
                int c = wv * 64 + ct * 16 + 4 * lg + r;   // D row = m = c
                int i = ibase + it * 16 + lr;             // D col = n = i
                hT[(size_t)c * N_NODES + i] = f2bf(acc[ct][it][r]);
            }
}

// B: fused masked-softmax(P) + P@h over a K-range; fp32 partial O and row-sum out
__launch_bounds__(256)
__global__ void k_attn(const int* __restrict__ adj, const short* __restrict__ hT,
                       const float* __restrict__ f1, const float* __restrict__ f2,
                       const float* __restrict__ F2maxp, float* __restrict__ part,
                       float* __restrict__ psum) {
    __shared__ short h_lds[256 * 64];   // hT slice [c][k], 128B rows, XOR swizzle
    const int tid = threadIdx.x;
    const int wv = tid >> 6, l = tid & 63, lg = l >> 4, lr = l & 15;
    const int ksid = blockIdx.x >> 7;      // 0..3 (slow index: neighbors share hT slices in L2)
    const int rowblk = blockIdx.x & 127;
    const int r0 = rowblk * 64;
    const int myrow = r0 + wv * 16 + lr;   // A-fragment row for this lane
    const float F2m = *F2maxp;
    const float f1v = f1[myrow];
    const float e0 = f1v + F2m;
    const float cr = fmaxf(e0, 0.2f * e0);     // upper bound of row scores (monotone leaky)
    const float L2E = 1.44269504f;
    const float crl = cr * L2E;
    f32x4 acc[16];
    #pragma unroll
    for (int t = 0; t < 16; ++t) acc[t] = (f32x4){0.f, 0.f, 0.f, 0.f};
    float ps = 0.f;
    const int kbeg = ksid * KCHUNK;
    const int* arow = adj + (size_t)myrow * N_NODES;
    for (int k0 = kbeg; k0 < kbeg + KCHUNK; k0 += 64) {
        __syncthreads();
        {   // stage hT[0:256][k0:k0+64] -> LDS
            int cb = tid >> 3, ch = tid & 7;
            #pragma unroll
            for (int p = 0; p < 8; ++p) {
                int c = cb + 32 * p;
                short8 s = *(const short8*)(hT + (size_t)c * N_NODES + k0 + ch * 8);
                *(short8*)&h_lds[c * 64 + 8 * (ch ^ (c & 7))] = s;
            }
        }
        __syncthreads();
        #pragma unroll
        for (int ks = 0; ks < 2; ++ks) {
            const int kg = k0 + 32 * ks + 8 * lg;     // this lane's 8-k window
            const int4 av0 = *(const int4*)(arow + kg);
            const int4 av1 = *(const int4*)(arow + kg + 4);
            const float4 fa = *(const float4*)(f2 + kg);
            const float4 fb = *(const float4*)(f2 + kg + 4);
            const float f2v[8] = {fa.x, fa.y, fa.z, fa.w, fb.x, fb.y, fb.z, fb.w};
            const int   am[8]  = {av0.x, av0.y, av0.z, av0.w, av1.x, av1.y, av1.z, av1.w};
            short8 pa;
            #pragma unroll
            for (int j = 0; j < 8; ++j) {
                float ee = f1v + f2v[j];
                float le = fmaxf(ee, 0.2f * ee);                       // LeakyReLU
                float pv = (am[j] > 0) ? exp2f(fmaf(le, L2E, -crl)) : 0.f;
                ps += pv;
                pa[j] = f2bf(pv);
            }
            #pragma unroll
            for (int t = 0; t < 16; ++t) {
                int c = t * 16 + lr;
                short8 bfrag = *(short8*)&h_lds[c * 64 + 8 * ((lg + 4*ks) ^ (c & 7))];
                acc[t] = __builtin_amdgcn_mfma_f32_16x16x32_bf16(pa, bfrag, acc[t], 0, 0, 0);
            }
        }
    }
    ps += __shfl_xor(ps, 16);
    ps += __shfl_xor(ps, 32);
    if (lg == 0) psum[ksid * N_NODES + myrow] = ps;
    float* pb = part + (size_t)ksid * N_NODES * F_OUT;
    #pragma unroll
    for (int t = 0; t < 16; ++t)
        #pragma unroll
        for (int r = 0; r < 4; ++r) {
            int row = r0 + wv * 16 + 4 * lg + r;   // D row = 4*(lane>>4)+reg
            int c = t * 16 + lr;                   // D col = lane&15
            pb[(size_t)row * F_OUT + c] = acc[t][r];
        }
}

// C: out = ELU( (sum_s part) / (sum_s psum) )
__global__ void k_comb(const float* __restrict__ part, const float* __restrict__ psum,
                       float* __restrict__ out) {
    const int i = blockIdx.x, c = threadIdx.x;
    float o = 0.f, s = 0.f;
    #pragma unroll
    for (int q = 0; q < KSPLIT; ++q) {
        o += part[(size_t)q * N_NODES * F_OUT + (size_t)i * F_OUT + c];
        s += psum[q * N_NODES + i];
    }
    float v = o / s;
    out[(size_t)i * F_OUT + c] = (v > 0.f) ? v : expm1f(v);
}

extern "C" void kernel_launch(void* const* d_in, const int* in_sizes, int n_in,
                              void* d_out, int out_size, void* d_ws, size_t ws_size,
                              hipStream_t stream) {
    const float* x  = (const float*)d_in[0];
    const int* adj  = (const int*)d_in[1];
    const float* W  = (const float*)d_in[2];
    const float* a1 = (const float*)d_in[3];
    const float* a2 = (const float*)d_in[4];
    float* out = (float*)d_out;

    // workspace layout (~36.5 MB)
    short* hT  = (short*)d_ws;                          // [256][8192] bf16
    short* WTg = hT + (size_t)F_OUT * N_NODES;          // [256][512] bf16
    float* fb  = (float*)(WTg + (size_t)F_OUT * F_IN);
    float* w1   = fb;
    float* w2   = fb + 512;
    float* f1   = fb + 1024;
    float* f2   = fb + 1024 + N_NODES;
    float* F2m  = fb + 1024 + 2 * N_NODES;
    float* part = fb + 32768;                           // [4][8192][256] f32
    float* psum = part + (size_t)KSPLIT * N_NODES * F_OUT;  // [4][8192] f32

    k_prep<<<F_IN, 64, 0, stream>>>(W, a1, a2, w1, w2, WTg);
    k_f12<<<N_NODES / 4, 256, 0, stream>>>(x, w1, w2, f1, f2);
    k_f2max<<<1, 1024, 0, stream>>>(f2, F2m);
    k_hT<<<N_NODES / 32, 256, 0, stream>>>(x, WTg, hT);
    k_attn<<<128 * KSPLIT, 256, 0, stream>>>(adj, hT, f1, f2, F2m, part, psum);
    k_comb<<<N_NODES, 256, 0, stream>>>(part, psum, out);
}